// Round 2
// baseline (13608.617 us; speedup 1.0000x reference)
//
#include <hip/hip_runtime.h>
#include <math.h>

// ---------------- workspace layout (float offsets) ----------------
#define OFF_HEADT   0L            // [9][67][128]            = 77184
#define OFF_REST    77184L        // [7][9][128][128]        = 1032192
#define OFF_FUST    1109376L      // [1024][256]             = 262144
#define OFF_W1T     1371520L      // [1280][512]             = 655360
#define OFF_W2T     2026880L      // [256][128]              = 32768
// total = 2,059,648 floats = 8.24 MB  (no states buffer — all fused in-block)

// ---------------- weight repack: make out-channel contiguous ----------------
__global__ void k_repack(const float* __restrict__ head_w, const float* __restrict__ res_w,
                         const float* __restrict__ fusion_w,
                         const float* __restrict__ pred1_w, const float* __restrict__ cls1_w,
                         const float* __restrict__ pred2_w, const float* __restrict__ cls2_w,
                         float* __restrict__ ws) {
  long j = (long)blockIdx.x * 256 + threadIdx.x;
  if (j < 77184) {            // headT[k][i][o] <- head_w[o][i][k]
    int o = j & 127; long r = j >> 7; int i = (int)(r % 67); int k = (int)(r / 67);
    ws[OFF_HEADT + j] = head_w[(o * 67 + i) * 9 + k];
  } else if ((j -= 77184) < 1032192) {   // resT[l][k][i][o] <- res_w[l][o][i][k]
    int o = j & 127; long r = j >> 7; int i = (int)(r & 127); r >>= 7;
    int k = (int)(r % 9); int l = (int)(r / 9);
    ws[OFF_REST + j] = res_w[(((long)(l * 128 + o)) * 128 + i) * 9 + k];
  } else if ((j -= 1032192) < 262144) {  // fusT[c][o] <- fusion_w[o][c]
    int o = j & 255; int c = (int)(j >> 8);
    ws[OFF_FUST + j] = fusion_w[(long)o * 1024 + c];
  } else if ((j -= 262144) < 655360) {   // W1T[c][o]: o<256 pred1, else cls1
    int o = j & 511; int c = (int)(j >> 9);
    ws[OFF_W1T + j] = (o < 256) ? pred1_w[(long)o * 1280 + c] : cls1_w[(long)(o - 256) * 1280 + c];
  } else if ((j -= 655360) < 32768) {    // W2T[r][j]: j<64 pred2, else cls2
    int jc = j & 127; int r = (int)(j >> 7);
    ws[OFF_W2T + j] = (jc < 64) ? pred2_w[jc * 256 + r] : cls2_w[(jc - 64) * 256 + r];
  }
}

// ---------------- circular dilated conv inner loop ----------------
// sx: [C_in][128] activations in LDS. wT: [9][C_in][128] (out-ch contiguous, wave-uniform -> s_load).
__device__ __forceinline__ void conv_inner(const float* __restrict__ sx,
                                           const float* __restrict__ wT,
                                           int C_in, int dil, int p, int o0,
                                           float acc[32]) {
  for (int k = 0; k < 9; k++) {
    const int xp = (p + (k - 4) * dil + 512) & 127;
    const float* xcol = sx + xp;
    const float* wk = wT + (long)(k * C_in) * 128 + o0;
    for (int i = 0; i < C_in; i++) {
      const float xv = xcol[i * 128];
      const float* w = wk + (long)i * 128;
#pragma unroll
      for (int oo = 0; oo < 32; oo++) acc[oo] = fmaf(w[oo], xv, acc[oo]);
    }
  }
}

// incremental fusion + pred1/cls1 accumulation for one 128-channel concat slot
__device__ __forceinline__ void accum_slot(const float* __restrict__ sx,
                                           const float* __restrict__ fusW,  // fusT + slot*128*256 + o64
                                           const float* __restrict__ h1W,   // W1T + (256+slot*128)*512 + o128
                                           int p, float fus[64], float h1[128]) {
  for (int i = 0; i < 128; i++) {
    const float xv = sx[i * 128 + p];
    const float* wf = fusW + (long)i * 256;
    const float* wh = h1W + (long)i * 512;
#pragma unroll
    for (int oo = 0; oo < 64; oo++) fus[oo] = fmaf(wf[oo], xv, fus[oo]);
#pragma unroll
    for (int oo = 0; oo < 128; oo++) h1[oo] = fmaf(wh[oo], xv, h1[oo]);
  }
}

// ---------------- fully fused per-polygon kernel ----------------
__global__ void __launch_bounds__(512)
k_fused(const float* __restrict__ cnn, const float* __restrict__ i_it,
        const float* __restrict__ c_it, const float* __restrict__ cls_in,
        const int* __restrict__ ind,
        const float* __restrict__ headT, const float* __restrict__ head_b,
        const float* __restrict__ resT, const float* __restrict__ res_b,
        const float* __restrict__ fusT, const float* __restrict__ fus_b,
        const float* __restrict__ W1T, const float* __restrict__ p1b, const float* __restrict__ c1b,
        const float* __restrict__ W2T, const float* __restrict__ p2b, const float* __restrict__ c2b,
        const float* __restrict__ p3w, const float* __restrict__ p3b,
        const float* __restrict__ c3w, const float* __restrict__ c3b,
        float* __restrict__ out) {
  __shared__ float sx[16384];     // 64 KB multi-use: [128][128] activations, then reductions/h2
  const int n = blockIdx.x, t = threadIdx.x;
  const int p = t & 127, og = t >> 7;          // og in 0..3, wave-uniform
  const int o32  = __builtin_amdgcn_readfirstlane(og * 32);
  const int o64  = __builtin_amdgcn_readfirstlane(og * 64);
  const int o128 = __builtin_amdgcn_readfirstlane(og * 128);

  // ---- bilinear gather (grid_sample, align_corners=False, zero pad) ----
  {
    const float gx = i_it[((long)n * 128 + p) * 2 + 0] - 0.5f;
    const float gy = i_it[((long)n * 128 + p) * 2 + 1] - 0.5f;
    const float fx = floorf(gx), fy = floorf(gy);
    const float wx = gx - fx, wy = gy - fy;
    const int x0 = (int)fx, y0 = (int)fy, x1 = x0 + 1, y1 = y0 + 1;
    const bool vx0 = (x0 >= 0) & (x0 < 128), vx1 = (x1 >= 0) & (x1 < 128);
    const bool vy0 = (y0 >= 0) & (y0 < 128), vy1 = (y1 >= 0) & (y1 < 128);
    const int x0c = min(max(x0, 0), 127), x1c = min(max(x1, 0), 127);
    const int y0c = min(max(y0, 0), 127), y1c = min(max(y1, 0), 127);
    const float w00 = (vx0 && vy0) ? (1.f - wx) * (1.f - wy) : 0.f;
    const float w01 = (vx1 && vy0) ? wx * (1.f - wy) : 0.f;
    const float w10 = (vx0 && vy1) ? (1.f - wx) * wy : 0.f;
    const float w11 = (vx1 && vy1) ? wx * wy : 0.f;
    const long base = (long)ind[n] * 64 * 16384;
    const int a00 = y0c * 128 + x0c, a01 = y0c * 128 + x1c;
    const int a10 = y1c * 128 + x0c, a11 = y1c * 128 + x1c;
    for (int cc = 0; cc < 16; cc++) {
      const int c = og * 16 + cc;
      const float* f = cnn + base + (long)c * 16384;
      sx[c * 128 + p] = f[a00] * w00 + f[a01] * w01 + f[a10] * w10 + f[a11] * w11;
    }
  }
  if (og == 0) {
    sx[64 * 128 + p] = c_it[((long)n * 128 + p) * 2 + 0] * 4.0f;
    sx[65 * 128 + p] = c_it[((long)n * 128 + p) * 2 + 1] * 4.0f;
    sx[66 * 128 + p] = cls_in[(long)n * 128 + p];
  }
  __syncthreads();

  float fus[64];
  float h1[128];
#pragma unroll
  for (int oo = 0; oo < 64; oo++) fus[oo] = 0.f;
#pragma unroll
  for (int oo = 0; oo < 128; oo++) h1[oo] = 0.f;

  // ---- head conv (C_in=67, dil=1) + relu -> slot 0 ----
  {
    float acc[32];
#pragma unroll
    for (int oo = 0; oo < 32; oo++) acc[oo] = head_b[o32 + oo];
    conv_inner(sx, headT, 67, 1, p, o32, acc);
    __syncthreads();            // all reads of x done
#pragma unroll
    for (int oo = 0; oo < 32; oo++) sx[(o32 + oo) * 128 + p] = fmaxf(acc[oo], 0.f);
    __syncthreads();
  }
  accum_slot(sx, fusT + o64, W1T + 256L * 512 + o128, p, fus, h1);

  // ---- 7 residual dilated conv layers, accumulating fusion/pred1/cls1 per slot ----
  for (int l = 0; l < 7; l++) {
    const int dil = (l >= 5) ? 4 : ((l >= 3) ? 2 : 1);   // 1,1,1,2,2,4,4
    float acc[32];
#pragma unroll
    for (int oo = 0; oo < 32; oo++) acc[oo] = res_b[l * 128 + o32 + oo];
    conv_inner(sx, resT + (long)l * 9 * 128 * 128, 128, dil, p, o32, acc);
    __syncthreads();            // all reads of state l done
#pragma unroll
    for (int oo = 0; oo < 32; oo++) {
      const float v = fmaxf(acc[oo], 0.f) + sx[(o32 + oo) * 128 + p];  // residual
      sx[(o32 + oo) * 128 + p] = v;
    }
    __syncthreads();
    accum_slot(sx, fusT + (long)(l + 1) * 128 * 256 + o64,
               W1T + (long)(256 + (l + 1) * 128) * 512 + o128, p, fus, h1);
  }

  // ---- phase B: fusion max over p -> g[256]; h1 += bias + W1g.g; relu ----
#pragma unroll
  for (int oo = 0; oo < 64; oo++) {
    float v = fus[oo];
#pragma unroll
    for (int s = 32; s > 0; s >>= 1) v = fmaxf(v, __shfl_xor(v, s, 64));
    fus[oo] = v;
  }
  __syncthreads();              // sx (state 7) no longer needed
  const int wv = t >> 6;        // wave id 0..7
  if ((t & 63) == 0) {
#pragma unroll
    for (int oo = 0; oo < 64; oo++) sx[wv * 64 + oo] = fus[oo];
  }
  __syncthreads();
  if (t < 256) {
    const int gg = t >> 6, oo = t & 63;
    sx[512 + t] = fmaxf(sx[(2 * gg) * 64 + oo], sx[(2 * gg + 1) * 64 + oo]) + fus_b[t];
  }
  __syncthreads();
  {
    // h1 init for output o = t: bias + W1[:,o] . g   (coalesced: lane t reads o=t column)
    float s = (t < 256) ? p1b[t] : c1b[t - 256];
    const float* w = W1T + t;
    for (int c = 0; c < 256; c++) s = fmaf(w[(long)c * 512], sx[512 + c], s);
    sx[1024 + t] = s;
  }
  __syncthreads();
#pragma unroll
  for (int oo = 0; oo < 128; oo++) h1[oo] = fmaxf(h1[oo] + sx[1024 + o128 + oo], 0.f);
  __syncthreads();              // before reusing sx for chunks

  // ---- phase C: pred2/cls2 (256->64 each), chunked through LDS ----
  const int j0 = __builtin_amdgcn_readfirstlane(og * 32);  // j in 0..127; j<64 pred2, j>=64 cls2
  float acc2[32];
#pragma unroll
  for (int jj = 0; jj < 32; jj++) acc2[jj] = 0.f;
  for (int c = 0; c < 8; c++) {
    if (og == (c >> 1)) {       // owner writes h1 channels 64c..64c+63 to sx[0..8191]
#pragma unroll
      for (int ii = 0; ii < 64; ii++) sx[ii * 128 + p] = h1[(c & 1) * 64 + ii];
    }
    __syncthreads();
    if ((og < 2) == (c < 4)) {  // pred2 consumes chunks 0..3 (h1 0..255), cls2 chunks 4..7
      const float* wb = W2T + (long)((c & 3) * 64) * 128 + j0;
      for (int i = 0; i < 64; i++) {
        const float xv = sx[i * 128 + p];
        const float* w = wb + (long)i * 128;
#pragma unroll
        for (int jj = 0; jj < 32; jj++) acc2[jj] = fmaf(w[jj], xv, acc2[jj]);
      }
    }
    __syncthreads();
  }
#pragma unroll
  for (int jj = 0; jj < 32; jj++) {
    const int j = j0 + jj;
    const float b = (j < 64) ? p2b[j] : c2b[j - 64];
    sx[j * 128 + p] = fmaxf(acc2[jj] + b, 0.f);   // h2[j][p]
  }
  __syncthreads();

  // ---- phase D: pred3/cls3 + outputs + NMS ----
  float sig = 0.f;
  if (t < 128) {
    float o0v = p3b[0], o1v = p3b[1], cv = c3b[0];
    for (int j = 0; j < 64; j++) {
      const float hp = sx[j * 128 + p];
      const float hc = sx[(64 + j) * 128 + p];
      o0v = fmaf(p3w[j], hp, o0v);
      o1v = fmaf(p3w[64 + j], hp, o1v);
      cv = fmaf(c3w[j], hc, cv);
    }
    const long ip = ((long)n * 128 + p) * 2;
    out[ip + 0] = i_it[ip + 0] * 4.f + o0v;
    out[ip + 1] = i_it[ip + 1] * 4.f + o1v;
    out[131072 + (long)n * 128 + p] = cv;
    sig = 1.f / (1.f + expf(-cv));
  }
  __syncthreads();
  if (t < 128) sx[p] = sig;
  __syncthreads();
  if (t < 128) {
    float m = sx[p];
#pragma unroll
    for (int s = 1; s <= 2; s++) {
      m = fmaxf(m, sx[(p + s) & 127]);
      m = fmaxf(m, sx[(p + 128 - s) & 127]);
    }
    out[196608 + (long)n * 128 + p] = (sig >= m) ? sig : 0.f;
  }
}

extern "C" void kernel_launch(void* const* d_in, const int* in_sizes, int n_in,
                              void* d_out, int out_size, void* d_ws, size_t ws_size,
                              hipStream_t stream) {
  const float* cnn      = (const float*)d_in[0];
  const float* i_it     = (const float*)d_in[1];
  const float* c_it     = (const float*)d_in[2];
  const float* it_cls   = (const float*)d_in[3];
  const int*   ind      = (const int*)d_in[4];
  const float* head_w   = (const float*)d_in[5];
  const float* head_b   = (const float*)d_in[6];
  const float* res_w    = (const float*)d_in[7];
  const float* res_b    = (const float*)d_in[8];
  const float* fusion_w = (const float*)d_in[9];
  const float* fusion_b = (const float*)d_in[10];
  const float* pred1_w  = (const float*)d_in[11];
  const float* pred1_b  = (const float*)d_in[12];
  const float* pred2_w  = (const float*)d_in[13];
  const float* pred2_b  = (const float*)d_in[14];
  const float* pred3_w  = (const float*)d_in[15];
  const float* pred3_b  = (const float*)d_in[16];
  const float* cls1_w   = (const float*)d_in[17];
  const float* cls1_b   = (const float*)d_in[18];
  const float* cls2_w   = (const float*)d_in[19];
  const float* cls2_b   = (const float*)d_in[20];
  const float* cls3_w   = (const float*)d_in[21];
  const float* cls3_b   = (const float*)d_in[22];
  float* ws = (float*)d_ws;
  float* out = (float*)d_out;

  // repack weights (2,059,648 elems -> 8.24 MB of ws)
  k_repack<<<8047, 256, 0, stream>>>(head_w, res_w, fusion_w, pred1_w, cls1_w, pred2_w, cls2_w, ws);
  // fully fused per-polygon network
  k_fused<<<512, 512, 0, stream>>>(cnn, i_it, c_it, it_cls, ind,
                                   ws + OFF_HEADT, head_b, ws + OFF_REST, res_b,
                                   ws + OFF_FUST, fusion_b,
                                   ws + OFF_W1T, pred1_b, cls1_b,
                                   ws + OFF_W2T, pred2_b, cls2_b,
                                   pred3_w, pred3_b, cls3_w, cls3_b,
                                   out);
}

// Round 3
// 5483.461 us; speedup vs baseline: 2.4818x; 2.4818x over previous
//
#include <hip/hip_runtime.h>
#include <math.h>

// ---------------- workspace layout (float offsets) ----------------
// CW: conv weights [8 layers][9 k][128 i][128 o]  (layer 0 = head, zero-padded i>=67)
#define OFF_CW      0L            // 8*9*128*128 = 1179648
#define OFF_FUST    1179648L      // fusT[1024][256]  = 262144
#define OFF_W1T     1441792L      // W1T[1280][512]   = 655360
#define OFF_W2T     2097152L      // W2T[256][128]    = 32768
#define WS_TOTAL    2129920L      // 8.52 MB

// ---------------- weight repack ----------------
__global__ void k_repack(const float* __restrict__ head_w, const float* __restrict__ res_w,
                         const float* __restrict__ fusion_w,
                         const float* __restrict__ pred1_w, const float* __restrict__ cls1_w,
                         const float* __restrict__ pred2_w, const float* __restrict__ cls2_w,
                         float* __restrict__ ws) {
  long j = (long)blockIdx.x * 256 + threadIdx.x;
  if (j >= WS_TOTAL) return;
  if (j < 1179648) {           // CW[l][k][i][o]
    int o = (int)(j & 127); long r = j >> 7;
    int i = (int)(r & 127); r >>= 7;
    int k = (int)(r % 9); int l = (int)(r / 9);
    float v;
    if (l == 0) v = (i < 67) ? head_w[(o * 67 + i) * 9 + k] : 0.f;
    else        v = res_w[((((l - 1) * 128 + o) * 128) + i) * 9 + k];
    ws[OFF_CW + j] = v;
  } else if ((j -= 1179648) < 262144) {   // fusT[c][o] <- fusion_w[o][c]
    int o = (int)(j & 255); int c = (int)(j >> 8);
    ws[OFF_FUST + j] = fusion_w[(long)o * 1024 + c];
  } else if ((j -= 262144) < 655360) {    // W1T[c][o]: o<256 pred1 else cls1
    int o = (int)(j & 511); int c = (int)(j >> 9);
    ws[OFF_W1T + j] = (o < 256) ? pred1_w[(long)o * 1280 + c] : cls1_w[(long)(o - 256) * 1280 + c];
  } else if ((j -= 655360) < 32768) {     // W2T[r][j]: j<64 pred2 else cls2
    int jc = (int)(j & 127); int r = (int)(j >> 7);
    ws[OFF_W2T + j] = (jc < 64) ? pred2_w[jc * 256 + r] : cls2_w[(jc - 64) * 256 + r];
  }
}

// ---------------- fully fused per-polygon kernel ----------------
// 512 threads = 8 waves. og = wave (t>>6), po = lane (t&63).
// Each lane: positions {po, po+64}; conv out-ch og*16..+15; fus out og*32..+31; h1 out og*64..+63.
__global__ void __launch_bounds__(512, 2)
k_fused(const float* __restrict__ cnn, const float* __restrict__ i_it,
        const float* __restrict__ c_it, const float* __restrict__ cls_in,
        const int* __restrict__ ind,
        const float* __restrict__ CW, const float* __restrict__ head_b, const float* __restrict__ res_b,
        const float* __restrict__ fusT, const float* __restrict__ fus_b,
        const float* __restrict__ W1T, const float* __restrict__ p1b, const float* __restrict__ c1b,
        const float* __restrict__ W2T, const float* __restrict__ p2b, const float* __restrict__ c2b,
        const float* __restrict__ p3w, const float* __restrict__ p3b,
        const float* __restrict__ c3w, const float* __restrict__ c3b,
        float* __restrict__ out) {
  __shared__ float sx[16384];    // activations [128 ch][128 pos] (64 KB)
  __shared__ float wbuf[8192];   // weight staging, 2 x 16 KB halves (32 KB)
  const int n = blockIdx.x, t = threadIdx.x;
  const int po = t & 63;
  const int og = __builtin_amdgcn_readfirstlane(t >> 6);   // 0..7, wave-uniform

  // ---- bilinear gather (uses p4 = t&127, og4 = t>>7 mapping) ----
  {
    const int p4 = t & 127, og4 = t >> 7;
    const float gx = i_it[((long)n * 128 + p4) * 2 + 0] - 0.5f;
    const float gy = i_it[((long)n * 128 + p4) * 2 + 1] - 0.5f;
    const float fx = floorf(gx), fy = floorf(gy);
    const float wx = gx - fx, wy = gy - fy;
    const int x0 = (int)fx, y0 = (int)fy, x1 = x0 + 1, y1 = y0 + 1;
    const bool vx0 = (x0 >= 0) & (x0 < 128), vx1 = (x1 >= 0) & (x1 < 128);
    const bool vy0 = (y0 >= 0) & (y0 < 128), vy1 = (y1 >= 0) & (y1 < 128);
    const int x0c = min(max(x0, 0), 127), x1c = min(max(x1, 0), 127);
    const int y0c = min(max(y0, 0), 127), y1c = min(max(y1, 0), 127);
    const float w00 = (vx0 && vy0) ? (1.f - wx) * (1.f - wy) : 0.f;
    const float w01 = (vx1 && vy0) ? wx * (1.f - wy) : 0.f;
    const float w10 = (vx0 && vy1) ? (1.f - wx) * wy : 0.f;
    const float w11 = (vx1 && vy1) ? wx * wy : 0.f;
    const long base = (long)ind[n] * 64 * 16384;
    const int a00 = y0c * 128 + x0c, a01 = y0c * 128 + x1c;
    const int a10 = y1c * 128 + x0c, a11 = y1c * 128 + x1c;
    for (int cc = 0; cc < 16; cc++) {
      const int c = og4 * 16 + cc;
      const float* f = cnn + base + (long)c * 16384;
      sx[c * 128 + p4] = f[a00] * w00 + f[a01] * w01 + f[a10] * w10 + f[a11] * w11;
    }
    if (og4 == 0) {
      sx[64 * 128 + p4] = c_it[((long)n * 128 + p4) * 2 + 0] * 4.0f;
      sx[65 * 128 + p4] = c_it[((long)n * 128 + p4) * 2 + 1] * 4.0f;
      sx[66 * 128 + p4] = cls_in[(long)n * 128 + p4];
    }
  }
  // zero pad rows 67..127 (head conv treats C_in as 128)
  for (int idx = t; idx < 61 * 128; idx += 512) sx[67 * 128 + idx] = 0.f;
  __syncthreads();

  float fus0[32], fus1[32], h10[64], h11[64];
#pragma unroll
  for (int oo = 0; oo < 32; oo++) { fus0[oo] = 0.f; fus1[oo] = 0.f; }
#pragma unroll
  for (int oo = 0; oo < 64; oo++) { h10[oo] = 0.f; h11[oo] = 0.f; }

  // ================= phase A: 8 conv layers + incremental fus/h1 =================
  for (int l = 0; l < 8; l++) {
    const int dil = (l >= 6) ? 4 : ((l >= 4) ? 2 : 1);
    const float* wl = CW + (long)l * 147456;
    const float* bias = (l == 0) ? head_b : (res_b + (l - 1) * 128);

    // ---- conv: 36 chunks of (1 k, 32 i) = 16 KB, double-buffered ----
    float acc0[16], acc1[16];
#pragma unroll
    for (int oo = 0; oo < 16; oo++) { acc0[oo] = bias[og * 16 + oo]; acc1[oo] = acc0[oo]; }
    { // stage chunk 0
      const float4* s = (const float4*)wl;
      float4 a = s[t * 2], b = s[t * 2 + 1];
      ((float4*)wbuf)[t * 2] = a; ((float4*)wbuf)[t * 2 + 1] = b;
    }
    __syncthreads();
    for (int cidx = 0; cidx < 36; cidx++) {
      float4 pa, pb;
      const bool pref = (cidx + 1) < 36;
      if (pref) {
        const float4* s = (const float4*)(wl + (long)(cidx + 1) * 4096);
        pa = s[t * 2]; pb = s[t * 2 + 1];
      }
      const int k = cidx >> 2;
      const int off = (k - 4) * dil;
      const int xa0 = (po + off + 128) & 127;
      const int xa1 = (po + 64 + off + 128) & 127;
      const float* wb = wbuf + (cidx & 1) * 4096 + og * 16;
      const float* xrow = sx + (cidx & 3) * 32 * 128;
      for (int i = 0; i < 32; i++) {
        const float xv0 = xrow[i * 128 + xa0];
        const float xv1 = xrow[i * 128 + xa1];
        const float* w = wb + i * 128;
#pragma unroll
        for (int oo = 0; oo < 16; oo++) {
          acc0[oo] = fmaf(w[oo], xv0, acc0[oo]);
          acc1[oo] = fmaf(w[oo], xv1, acc1[oo]);
        }
      }
      if (pref) {
        float4* d = (float4*)(wbuf + ((cidx + 1) & 1) * 4096);
        d[t * 2] = pa; d[t * 2 + 1] = pb;
      }
      __syncthreads();
    }
    // relu + residual + write back (each element owned by exactly one lane)
#pragma unroll
    for (int oo = 0; oo < 16; oo++) {
      const int o = og * 16 + oo;
      float v0 = fmaxf(acc0[oo], 0.f);
      float v1 = fmaxf(acc1[oo], 0.f);
      if (l > 0) { v0 += sx[o * 128 + po]; v1 += sx[o * 128 + po + 64]; }
      sx[o * 128 + po] = v0;
      sx[o * 128 + po + 64] = v1;
    }
    __syncthreads();

    // ---- incremental fusion + pred1/cls1: 32 chunks of 4 i (12 KB), double-buffered ----
    const float* fusW = fusT + (long)l * 32768;               // [128 i][256 o]
    const float* h1W  = W1T + (long)(256 + l * 128) * 512;    // [128 i][512 o]
    { // stage chunk 0
      float2 f = ((const float2*)fusW)[t];
      float4 h = ((const float4*)h1W)[t];
      ((float2*)wbuf)[t] = f;
      ((float4*)(wbuf + 1024))[t] = h;
    }
    __syncthreads();
    for (int c = 0; c < 32; c++) {
      float2 pf; float4 ph;
      const bool pr = (c + 1) < 32;
      if (pr) {
        pf = ((const float2*)(fusW + (long)(c + 1) * 1024))[t];
        ph = ((const float4*)(h1W + (long)(c + 1) * 2048))[t];
      }
      const float* wb = wbuf + (c & 1) * 4096;
      const float* xrow = sx + c * 4 * 128;
      for (int i = 0; i < 4; i++) {
        const float xv0 = xrow[i * 128 + po];
        const float xv1 = xrow[i * 128 + po + 64];
        const float* wf = wb + i * 256 + og * 32;
        const float* wh = wb + 1024 + i * 512 + og * 64;
#pragma unroll
        for (int oo = 0; oo < 32; oo++) {
          fus0[oo] = fmaf(wf[oo], xv0, fus0[oo]);
          fus1[oo] = fmaf(wf[oo], xv1, fus1[oo]);
        }
#pragma unroll
        for (int oo = 0; oo < 64; oo++) {
          h10[oo] = fmaf(wh[oo], xv0, h10[oo]);
          h11[oo] = fmaf(wh[oo], xv1, h11[oo]);
        }
      }
      if (pr) {
        float* wn = wbuf + ((c + 1) & 1) * 4096;
        ((float2*)wn)[t] = pf;
        ((float4*)(wn + 1024))[t] = ph;
      }
      __syncthreads();
    }
  }

  // ================= phase B: fusion max -> g; h1 += bias + W1g.g; relu =================
#pragma unroll
  for (int oo = 0; oo < 32; oo++) {
    float v = fmaxf(fus0[oo], fus1[oo]);
#pragma unroll
    for (int s = 32; s > 0; s >>= 1) v = fmaxf(v, __shfl_xor(v, s, 64));
    if (po == 0) sx[256 + og * 32 + oo] = v;   // raw max per fusion output
  }
  __syncthreads();
  if (t < 256) sx[t] = sx[256 + t] + fus_b[t];  // g[c]
  __syncthreads();
  {
    // hg[o] = bias + sum_{c<256} W1T[c][o] * g[c], o = t (coalesced column reads)
    float s = (t < 256) ? p1b[t] : c1b[t - 256];
    const float* w = W1T + t;
    for (int c = 0; c < 256; c++) s = fmaf(w[(long)c * 512], sx[c], s);
    sx[512 + t] = s;
  }
  __syncthreads();
#pragma unroll
  for (int oo = 0; oo < 64; oo++) {
    const float hb = sx[512 + og * 64 + oo];
    h10[oo] = fmaxf(h10[oo] + hb, 0.f);
    h11[oo] = fmaxf(h11[oo] + hb, 0.f);
  }
  __syncthreads();

  // ================= phase C: pred2/cls2 (256->64 each) =================
  float a20[16], a21[16];
#pragma unroll
  for (int jj = 0; jj < 16; jj++) { a20[jj] = 0.f; a21[jj] = 0.f; }
  for (int c = 0; c < 8; c++) {
    if (og == c) {            // owner dumps its h1 chunk (64 ch x 128 pos)
#pragma unroll
      for (int oo = 0; oo < 64; oo++) {
        sx[oo * 128 + po] = h10[oo];
        sx[oo * 128 + po + 64] = h11[oo];
      }
    }
    { // stage W2T rows (c&3)*64..+64 into wbuf (32 KB)
      const float4* s = (const float4*)(W2T + (long)(c & 3) * 8192);
#pragma unroll
      for (int v = 0; v < 4; v++) ((float4*)wbuf)[t * 4 + v] = s[t * 4 + v];
    }
    __syncthreads();
    if ((og < 4) == (c < 4)) {   // og<4: pred2 (chunks 0-3); og>=4: cls2 (chunks 4-7)
      for (int i = 0; i < 64; i++) {
        const float xv0 = sx[i * 128 + po];
        const float xv1 = sx[i * 128 + po + 64];
        const float* w = wbuf + i * 128 + og * 16;
#pragma unroll
        for (int jj = 0; jj < 16; jj++) {
          a20[jj] = fmaf(w[jj], xv0, a20[jj]);
          a21[jj] = fmaf(w[jj], xv1, a21[jj]);
        }
      }
    }
    __syncthreads();
  }
#pragma unroll
  for (int jj = 0; jj < 16; jj++) {   // h2 rows: j<64 pred2, j>=64 cls2
    const int j = og * 16 + jj;
    const float b = (j < 64) ? p2b[j] : c2b[j - 64];
    sx[j * 128 + po] = fmaxf(a20[jj] + b, 0.f);
    sx[j * 128 + po + 64] = fmaxf(a21[jj] + b, 0.f);
  }
  __syncthreads();

  // ================= phase D: pred3/cls3 + outputs + NMS =================
  float sig = 0.f;
  const int p = t & 127;
  if (t < 128) {
    float o0v = p3b[0], o1v = p3b[1], cv = c3b[0];
    for (int j = 0; j < 64; j++) {
      const float hp = sx[j * 128 + p];
      const float hc = sx[(64 + j) * 128 + p];
      o0v = fmaf(p3w[j], hp, o0v);
      o1v = fmaf(p3w[64 + j], hp, o1v);
      cv = fmaf(c3w[j], hc, cv);
    }
    const long ip = ((long)n * 128 + p) * 2;
    out[ip + 0] = i_it[ip + 0] * 4.f + o0v;
    out[ip + 1] = i_it[ip + 1] * 4.f + o1v;
    out[131072 + (long)n * 128 + p] = cv;
    sig = 1.f / (1.f + expf(-cv));
  }
  __syncthreads();
  if (t < 128) sx[p] = sig;
  __syncthreads();
  if (t < 128) {
    float m = sx[p];
#pragma unroll
    for (int s = 1; s <= 2; s++) {
      m = fmaxf(m, sx[(p + s) & 127]);
      m = fmaxf(m, sx[(p + 128 - s) & 127]);
    }
    out[196608 + (long)n * 128 + p] = (sig >= m) ? sig : 0.f;
  }
}

extern "C" void kernel_launch(void* const* d_in, const int* in_sizes, int n_in,
                              void* d_out, int out_size, void* d_ws, size_t ws_size,
                              hipStream_t stream) {
  const float* cnn      = (const float*)d_in[0];
  const float* i_it     = (const float*)d_in[1];
  const float* c_it     = (const float*)d_in[2];
  const float* it_cls   = (const float*)d_in[3];
  const int*   ind      = (const int*)d_in[4];
  const float* head_w   = (const float*)d_in[5];
  const float* head_b   = (const float*)d_in[6];
  const float* res_w    = (const float*)d_in[7];
  const float* res_b    = (const float*)d_in[8];
  const float* fusion_w = (const float*)d_in[9];
  const float* fusion_b = (const float*)d_in[10];
  const float* pred1_w  = (const float*)d_in[11];
  const float* pred1_b  = (const float*)d_in[12];
  const float* pred2_w  = (const float*)d_in[13];
  const float* pred2_b  = (const float*)d_in[14];
  const float* pred3_w  = (const float*)d_in[15];
  const float* pred3_b  = (const float*)d_in[16];
  const float* cls1_w   = (const float*)d_in[17];
  const float* cls1_b   = (const float*)d_in[18];
  const float* cls2_w   = (const float*)d_in[19];
  const float* cls2_b   = (const float*)d_in[20];
  const float* cls3_w   = (const float*)d_in[21];
  const float* cls3_b   = (const float*)d_in[22];
  float* ws = (float*)d_ws;
  float* out = (float*)d_out;

  k_repack<<<(int)((WS_TOTAL + 255) / 256), 256, 0, stream>>>(
      head_w, res_w, fusion_w, pred1_w, cls1_w, pred2_w, cls2_w, ws);
  k_fused<<<512, 512, 0, stream>>>(cnn, i_it, c_it, it_cls, ind,
                                   ws + OFF_CW, head_b, res_b,
                                   ws + OFF_FUST, fusion_b,
                                   ws + OFF_W1T, pred1_b, cls1_b,
                                   ws + OFF_W2T, pred2_b, cls2_b,
                                   pred3_w, pred3_b, cls3_w, cls3_b,
                                   out);
}

// Round 4
// 4309.071 us; speedup vs baseline: 3.1581x; 1.2725x over previous
//
#include <hip/hip_runtime.h>
#include <math.h>

// ---------------- workspace layout (float offsets) ----------------
// CWP[l8][k9][ib4][wv16][i32][o8]  : conv weights, 1KB chunk per (l,k,ib,wv)
// FWH[l8][wv16][ic32][ii4][48]     : fusion(16)+h1(32) slices, 768B chunk per (l,wv,ic)
// W1G[c256][o512]                  : g-part of pred1/cls1
// W2P[cc4][wv16][i64][j8]          : pred2/cls2 slices, 2KB per (cc,wv)
#define OFF_CWP 0L
#define OFF_FWH 1179648L
#define OFF_W1G 1966080L
#define OFF_W2P 2097152L
#define WS_TOTAL 2129920L   // 8.52 MB

__global__ void k_repack(const float* __restrict__ head_w, const float* __restrict__ res_w,
                         const float* __restrict__ fusion_w,
                         const float* __restrict__ pred1_w, const float* __restrict__ cls1_w,
                         const float* __restrict__ pred2_w, const float* __restrict__ cls2_w,
                         float* __restrict__ ws) {
  long j = (long)blockIdx.x * 256 + threadIdx.x;
  if (j >= WS_TOTAL) return;
  if (j < OFF_FWH) {                      // CWP
    int o = (int)(j & 7); int i = (int)((j >> 3) & 31); int wv = (int)((j >> 8) & 15);
    int ib = (int)((j >> 12) & 3); long r = j >> 14; int k = (int)(r % 9); int l = (int)(r / 9);
    int og = (wv >> 1) * 16 + (wv & 1) * 8 + o;
    int ig = ib * 32 + i;
    float v;
    if (l == 0) v = (ig < 67) ? head_w[(og * 67 + ig) * 9 + k] : 0.f;
    else        v = res_w[(((l - 1) * 128 + og) * 128 + ig) * 9 + k];
    ws[j] = v;
  } else if (j < OFF_W1G) {               // FWH
    long j2 = j - OFF_FWH;
    int r = (int)(j2 % 48); long q = j2 / 48;
    int ii = (int)(q & 3); int ic = (int)((q >> 2) & 31); int wv = (int)((q >> 7) & 15); int l = (int)(q >> 11);
    int ig = ic * 4 + ii;
    float v;
    if (r < 16) { int fo = (wv >> 1) * 32 + (wv & 1) * 16 + r; v = fusion_w[(long)fo * 1024 + l * 128 + ig]; }
    else { int rr = r - 16; int ho = (wv >> 1) * 64 + (wv & 1) * 32 + rr; int c = 256 + l * 128 + ig;
           v = (ho < 256) ? pred1_w[(long)ho * 1280 + c] : cls1_w[(long)(ho - 256) * 1280 + c]; }
    ws[j] = v;
  } else if (j < OFF_W2P) {               // W1G
    long j3 = j - OFF_W1G; int o = (int)(j3 & 511); int c = (int)(j3 >> 9);
    ws[j] = (o < 256) ? pred1_w[(long)o * 1280 + c] : cls1_w[(long)(o - 256) * 1280 + c];
  } else {                                // W2P
    long j4 = j - OFF_W2P; int jj = (int)(j4 & 7); int i = (int)((j4 >> 3) & 63);
    int wv = (int)((j4 >> 9) & 15); int cc = (int)((j4 >> 13) & 3);
    int jg = (wv >> 1) * 16 + (wv & 1) * 8 + jj;
    ws[j] = (jg < 64) ? pred2_w[jg * 256 + cc * 64 + i] : cls2_w[(jg - 64) * 256 + cc * 64 + i];
  }
}

// async global->LDS (wave-uniform LDS base + lane*size)
__device__ __forceinline__ void cp16(const float* g, float* l) {
  __builtin_amdgcn_global_load_lds((const __attribute__((address_space(1))) unsigned int*)g,
                                   (__attribute__((address_space(3))) unsigned int*)l, 16, 0, 0);
}
__device__ __forceinline__ void cp12(const float* g, float* l) {
  __builtin_amdgcn_global_load_lds((const __attribute__((address_space(1))) unsigned int*)g,
                                   (__attribute__((address_space(3))) unsigned int*)l, 12, 0, 0);
}

// 1024 threads = 16 waves. wave wv owns: conv out-ch [ob,ob+8), fus [fb,fb+16), h1 [hb,hb+32).
// lane po handles positions po and po+64.
__global__ void __launch_bounds__(1024, 4)
k_fused(const float* __restrict__ cnn, const float* __restrict__ i_it,
        const float* __restrict__ c_it, const float* __restrict__ cls_in,
        const int* __restrict__ ind,
        const float* __restrict__ CWP, const float* __restrict__ FWH,
        const float* __restrict__ W1G, const float* __restrict__ W2P,
        const float* __restrict__ head_b, const float* __restrict__ res_b,
        const float* __restrict__ fus_b,
        const float* __restrict__ p1b, const float* __restrict__ c1b,
        const float* __restrict__ p2b, const float* __restrict__ c2b,
        const float* __restrict__ p3w, const float* __restrict__ p3b,
        const float* __restrict__ c3w, const float* __restrict__ c3b,
        float* __restrict__ out) {
  __shared__ float sx[16384];    // activations [128 ch][128 pos], 64 KB
  __shared__ float wbuf[8192];   // 16 waves x 2 x 256 floats private staging, 32 KB
  const int n = blockIdx.x, t = threadIdx.x;
  const int po = t & 63;
  const int wv = __builtin_amdgcn_readfirstlane(t >> 6);
  float* wb = wbuf + wv * 512;
  const int ob = (wv >> 1) * 16 + (wv & 1) * 8;
  const int fb = (wv >> 1) * 32 + (wv & 1) * 16;
  const int hb = (wv >> 1) * 64 + (wv & 1) * 32;

  // ---- bilinear gather ----
  {
    const int p4 = t & 127, og4 = t >> 7;
    const float gx = i_it[((long)n * 128 + p4) * 2 + 0] - 0.5f;
    const float gy = i_it[((long)n * 128 + p4) * 2 + 1] - 0.5f;
    const float fx = floorf(gx), fy = floorf(gy);
    const float wx = gx - fx, wy = gy - fy;
    const int x0 = (int)fx, y0 = (int)fy, x1 = x0 + 1, y1 = y0 + 1;
    const bool vx0 = (x0 >= 0) & (x0 < 128), vx1 = (x1 >= 0) & (x1 < 128);
    const bool vy0 = (y0 >= 0) & (y0 < 128), vy1 = (y1 >= 0) & (y1 < 128);
    const int x0c = min(max(x0, 0), 127), x1c = min(max(x1, 0), 127);
    const int y0c = min(max(y0, 0), 127), y1c = min(max(y1, 0), 127);
    const float w00 = (vx0 && vy0) ? (1.f - wx) * (1.f - wy) : 0.f;
    const float w01 = (vx1 && vy0) ? wx * (1.f - wy) : 0.f;
    const float w10 = (vx0 && vy1) ? (1.f - wx) * wy : 0.f;
    const float w11 = (vx1 && vy1) ? wx * wy : 0.f;
    const long base = (long)ind[n] * 64 * 16384;
    const int a00 = y0c * 128 + x0c, a01 = y0c * 128 + x1c;
    const int a10 = y1c * 128 + x0c, a11 = y1c * 128 + x1c;
    for (int cc = 0; cc < 8; cc++) {
      const int c = og4 * 8 + cc;
      const float* f = cnn + base + (long)c * 16384;
      sx[c * 128 + p4] = f[a00] * w00 + f[a01] * w01 + f[a10] * w10 + f[a11] * w11;
    }
    if (og4 == 0) {
      sx[64 * 128 + p4] = c_it[((long)n * 128 + p4) * 2 + 0] * 4.0f;
      sx[65 * 128 + p4] = c_it[((long)n * 128 + p4) * 2 + 1] * 4.0f;
      sx[66 * 128 + p4] = cls_in[(long)n * 128 + p4];
    }
  }
  if (t < 61 * 128) sx[67 * 128 + t] = 0.f;   // zero-pad rows 67..127
  __syncthreads();

  float f0[16], f1[16], h0[32], h1v[32];
#pragma unroll
  for (int r = 0; r < 16; r++) { f0[r] = 0.f; f1[r] = 0.f; }
#pragma unroll
  for (int r = 0; r < 32; r++) { h0[r] = 0.f; h1v[r] = 0.f; }

  // ================= phase A =================
  for (int l = 0; l < 8; l++) {
    const int dil = (l >= 6) ? 4 : ((l >= 4) ? 2 : 1);

    // ---- conv: 36 wave-private 1KB chunks (1 k, 32 i, 8 o), dbuf, no barriers ----
    float a0[8], a1[8];
    {
      const float* bsrc = (l == 0) ? (head_b + ob) : (res_b + (l - 1) * 128 + ob);
#pragma unroll
      for (int oo = 0; oo < 8; oo++) { a0[oo] = bsrc[oo]; a1[oo] = a0[oo]; }
    }
    const float* wl = CWP + (long)l * 147456 + wv * 256;
    cp16(wl + po * 4, wb);
    for (int c = 0; c < 36; c++) {
      if (c + 1 < 36) {
        cp16(wl + (long)(c + 1) * 4096 + po * 4, wb + ((c + 1) & 1) * 256);
        asm volatile("s_waitcnt vmcnt(1)" ::: "memory");
      } else {
        asm volatile("s_waitcnt vmcnt(0)" ::: "memory");
      }
      const int k = c >> 2, ib = c & 3;
      const int xa0 = (po + (k - 4) * dil + 128) & 127;
      const int xa1 = xa0 ^ 64;
      const float* w = wb + (c & 1) * 256;
      const float* xr = sx + ib * 32 * 128;
#pragma unroll 4
      for (int i = 0; i < 32; i++) {
        const float xv0 = xr[i * 128 + xa0];
        const float xv1 = xr[i * 128 + xa1];
        const float* wi = w + i * 8;
#pragma unroll
        for (int oo = 0; oo < 8; oo++) {
          a0[oo] = fmaf(wi[oo], xv0, a0[oo]);
          a1[oo] = fmaf(wi[oo], xv1, a1[oo]);
        }
      }
    }
    __syncthreads();
#pragma unroll
    for (int oo = 0; oo < 8; oo++) {
      const int o = ob + oo;
      float v0 = fmaxf(a0[oo], 0.f), v1 = fmaxf(a1[oo], 0.f);
      if (l > 0) { v0 += sx[o * 128 + po]; v1 += sx[o * 128 + po + 64]; }
      sx[o * 128 + po] = v0;
      sx[o * 128 + po + 64] = v1;
    }
    __syncthreads();

    // ---- fus/h1: 32 wave-private 768B chunks (4 i x 48), dbuf, no barriers ----
    const float* fl = FWH + ((long)l * 16 + wv) * 6144;
    cp12(fl + po * 3, wb);
    for (int ic = 0; ic < 32; ic++) {
      if (ic + 1 < 32) {
        cp12(fl + (long)(ic + 1) * 192 + po * 3, wb + ((ic + 1) & 1) * 256);
        asm volatile("s_waitcnt vmcnt(1)" ::: "memory");
      } else {
        asm volatile("s_waitcnt vmcnt(0)" ::: "memory");
      }
      const float* w = wb + (ic & 1) * 256;
#pragma unroll
      for (int ii = 0; ii < 4; ii++) {
        const int ig = ic * 4 + ii;
        const float xv0 = sx[ig * 128 + po];
        const float xv1 = sx[ig * 128 + po + 64];
        const float* wr = w + ii * 48;
#pragma unroll
        for (int r = 0; r < 16; r++) {
          f0[r] = fmaf(wr[r], xv0, f0[r]);
          f1[r] = fmaf(wr[r], xv1, f1[r]);
        }
#pragma unroll
        for (int r = 0; r < 32; r++) {
          h0[r] = fmaf(wr[16 + r], xv0, h0[r]);
          h1v[r] = fmaf(wr[16 + r], xv1, h1v[r]);
        }
      }
    }
  }

  // ================= phase B: g = max_p(fus)+b; h1 += bias + W1g.g; relu =================
  float gm[16];
#pragma unroll
  for (int r = 0; r < 16; r++) {
    float m = fmaxf(f0[r], f1[r]);
#pragma unroll
    for (int s = 32; s > 0; s >>= 1) m = fmaxf(m, __shfl_xor(m, s, 64));
    gm[r] = m;
  }
  __syncthreads();            // all fus/h1 reads of sx done
  if (po == 0) {
#pragma unroll
    for (int r = 0; r < 16; r++) sx[fb + r] = gm[r];
  }
  __syncthreads();
  if (t < 256) sx[256 + t] = sx[t] + fus_b[t];
  __syncthreads();
  if (t < 512) {
    float s = (t < 256) ? p1b[t] : c1b[t - 256];
    const float* w = W1G + t;
#pragma unroll 8
    for (int c = 0; c < 256; c++) s = fmaf(w[(long)c * 512], sx[256 + c], s);
    sx[512 + t] = s;
  }
  __syncthreads();
#pragma unroll
  for (int r = 0; r < 32; r++) {
    const float b = sx[512 + hb + r];
    h0[r] = fmaxf(h0[r] + b, 0.f);
    h1v[r] = fmaxf(h1v[r] + b, 0.f);
  }

  // ================= phase C: pred2/cls2 =================
  float a20[8], a21[8];
#pragma unroll
  for (int jj = 0; jj < 8; jj++) { a20[jj] = 0.f; a21[jj] = 0.f; }
  for (int c = 0; c < 8; c++) {
    __syncthreads();
    if ((wv >> 1) == c) {      // owners dump h1 rows c*64..c*64+63
#pragma unroll
      for (int r = 0; r < 32; r++) {
        sx[((wv & 1) * 32 + r) * 128 + po] = h0[r];
        sx[((wv & 1) * 32 + r) * 128 + po + 64] = h1v[r];
      }
    }
    const bool act = (ob < 64) == (c < 4);
    if (act) {
      const float* g2 = W2P + ((long)(c & 3) * 16 + wv) * 512;
      cp16(g2 + po * 4, wb);
      cp16(g2 + 256 + po * 4, wb + 256);
    }
    __syncthreads();
    if (act) {
      asm volatile("s_waitcnt vmcnt(0)" ::: "memory");
#pragma unroll 4
      for (int i = 0; i < 64; i++) {
        const float xv0 = sx[i * 128 + po];
        const float xv1 = sx[i * 128 + po + 64];
        const float* w = wb + i * 8;
#pragma unroll
        for (int jj = 0; jj < 8; jj++) {
          a20[jj] = fmaf(w[jj], xv0, a20[jj]);
          a21[jj] = fmaf(w[jj], xv1, a21[jj]);
        }
      }
    }
  }
  __syncthreads();
#pragma unroll
  for (int jj = 0; jj < 8; jj++) {   // h2 rows: j<64 pred2, j>=64 cls2
    const int j = ob + jj;
    const float b = (j < 64) ? p2b[j] : c2b[j - 64];
    sx[j * 128 + po] = fmaxf(a20[jj] + b, 0.f);
    sx[j * 128 + po + 64] = fmaxf(a21[jj] + b, 0.f);
  }
  __syncthreads();

  // ================= phase D: pred3/cls3 + outputs + NMS =================
  float sig = 0.f;
  const int p = t & 127;
  if (t < 128) {
    float o0v = p3b[0], o1v = p3b[1], cv = c3b[0];
    for (int j = 0; j < 64; j++) {
      const float hp = sx[j * 128 + p];
      const float hc = sx[(64 + j) * 128 + p];
      o0v = fmaf(p3w[j], hp, o0v);
      o1v = fmaf(p3w[64 + j], hp, o1v);
      cv = fmaf(c3w[j], hc, cv);
    }
    const long ip = ((long)n * 128 + p) * 2;
    out[ip + 0] = i_it[ip + 0] * 4.f + o0v;
    out[ip + 1] = i_it[ip + 1] * 4.f + o1v;
    out[131072 + (long)n * 128 + p] = cv;
    sig = 1.f / (1.f + expf(-cv));
  }
  __syncthreads();
  if (t < 128) sx[p] = sig;
  __syncthreads();
  if (t < 128) {
    float m = sx[p];
#pragma unroll
    for (int s = 1; s <= 2; s++) {
      m = fmaxf(m, sx[(p + s) & 127]);
      m = fmaxf(m, sx[(p + 128 - s) & 127]);
    }
    out[196608 + (long)n * 128 + p] = (sig >= m) ? sig : 0.f;
  }
}

extern "C" void kernel_launch(void* const* d_in, const int* in_sizes, int n_in,
                              void* d_out, int out_size, void* d_ws, size_t ws_size,
                              hipStream_t stream) {
  const float* cnn      = (const float*)d_in[0];
  const float* i_it     = (const float*)d_in[1];
  const float* c_it     = (const float*)d_in[2];
  const float* it_cls   = (const float*)d_in[3];
  const int*   ind      = (const int*)d_in[4];
  const float* head_w   = (const float*)d_in[5];
  const float* head_b   = (const float*)d_in[6];
  const float* res_w    = (const float*)d_in[7];
  const float* res_b    = (const float*)d_in[8];
  const float* fusion_w = (const float*)d_in[9];
  const float* fusion_b = (const float*)d_in[10];
  const float* pred1_w  = (const float*)d_in[11];
  const float* pred1_b  = (const float*)d_in[12];
  const float* pred2_w  = (const float*)d_in[13];
  const float* pred2_b  = (const float*)d_in[14];
  const float* pred3_w  = (const float*)d_in[15];
  const float* pred3_b  = (const float*)d_in[16];
  const float* cls1_w   = (const float*)d_in[17];
  const float* cls1_b   = (const float*)d_in[18];
  const float* cls2_w   = (const float*)d_in[19];
  const float* cls2_b   = (const float*)d_in[20];
  const float* cls3_w   = (const float*)d_in[21];
  const float* cls3_b   = (const float*)d_in[22];
  float* ws = (float*)d_ws;
  float* out = (float*)d_out;

  k_repack<<<(int)((WS_TOTAL + 255) / 256), 256, 0, stream>>>(
      head_w, res_w, fusion_w, pred1_w, cls1_w, pred2_w, cls2_w, ws);
  k_fused<<<512, 1024, 0, stream>>>(cnn, i_it, c_it, it_cls, ind,
                                    ws + OFF_CWP, ws + OFF_FWH, ws + OFF_W1G, ws + OFF_W2P,
                                    head_b, res_b, fusion_b,
                                    pred1_b, cls1_b, pred2_b, cls2_b,
                                    pred3_w, pred3_b, cls3_w, cls3_b,
                                    out);
}